// Round 11
// baseline (659.039 us; speedup 1.0000x reference)
//
#include <hip/hip_runtime.h>

// WaveCell v11: 2-wide threads for natural <=64-VGPR occupancy doubling.
// B=4, NZ=NX=2048, fp32, periodic wrap (pow2 dims).
//
// Falsified so far: HBM read volume (v4: 2.4x less, flat), request count
// (v1: 4.8x more, +28%), store path (v9: cached ~= NT - 8us), store-drain
// order (v8), CU-side request bytes (v10: LDS staging, regressed).
// Never cleanly varied: RESIDENT WAVES. All fast variants: VGPR 68-88 ->
// 4 waves/SIMD tier -> occ 21-32%. Forcing via launch_bounds spilled
// (v5/v6); v7 dieted persistent coeffs but peak live set = in-flight loads.
//
// v11: thread = 2 x-points x 4 shots (grid x2 = 8192 blocks). In-flight
// load set 62 -> 34 floats, coeffs 28 -> 22 -> target VGPR ~52-60 ->
// NATURAL 8 waves/SIMD (no forcing). Cost: 2x VMEM instrs per output
// (proven non-binding by v1) + float2 stores (write path has headroom per
// fill kernel 6.5 TB/s). Keep: XCD swizzle, cached stores, unroll-1.
// Pre-commit: VGPR<=64 && WRITE==320MiB else VOID; occ>=55% && t>=195us
// -> concurrency model dead, structural bound.

constexpr int NZ = 2048;
constexpr int NX = 2048;
constexpr int B  = 4;
constexpr int PLANE = NZ * NX;      // 4,194,304
constexpr int VOL   = B * PLANE;    // 16,777,216
constexpr float DT    = 1e-3f;
constexpr float INV_H = 0.1f;       // 1/10m
constexpr int NBLK = (PLANE / 2) / 256;    // 8192
constexpr int NXCD = 8;
constexpr int BLK_PER_XCD = NBLK / NXCD;   // 1024

typedef float f32x2 __attribute__((ext_vector_type(2)));

__device__ __forceinline__ float rcpf(float x) { return __builtin_amdgcn_rcpf(x); }
__device__ __forceinline__ f32x2 ld2(const float* __restrict__ p) {
    return *reinterpret_cast<const f32x2*>(p);
}
__device__ __forceinline__ void st2(float* __restrict__ p, float a, float b) {
    f32x2 v = {a, b};
    *reinterpret_cast<f32x2*>(p) = v;   // plain cached store (v9-proven)
}

__global__ __launch_bounds__(256) void wave_fused_v11(
    const float* __restrict__ vp,  const float* __restrict__ vs,
    const float* __restrict__ rho,
    const float* __restrict__ vx,  const float* __restrict__ vz,
    const float* __restrict__ txx, const float* __restrict__ tzz,
    const float* __restrict__ txz,
    const float* __restrict__ dd,
    float* __restrict__ out)
{
    // XCD-band swizzle: XCD k owns sb in [k*1024,(k+1)*1024) = a contiguous
    // 256-row z-band (4 blocks per z-row at width 2).
    const int bid = blockIdx.x;
    const int sb  = (bid & (NXCD - 1)) * BLK_PER_XCD + (bid >> 3);
    const int t   = sb * blockDim.x + threadIdx.x;          // [0, PLANE/2)
    const int xb  = (t & (NX / 2 - 1)) << 1;                // x base, %2==0
    const int z   = t >> 10;                                // t / (NX/2)
    const int zp  = (z + 1) & (NZ - 1);
    const int zm  = (z - 1) & (NZ - 1);
    const int xm1 = (xb - 1) & (NX - 1);
    const int xp2 = (xb + 2) & (NX - 1);
    const int rz  = z  * NX;
    const int rzp = zp * NX;
    const int rzm = zm * NX;

    // ---------- coefficients (22 persistent floats, amortized over shots) --
    // avz/bvz[j] <-> col xb-1+j (j=0..3); q*/[k], azp.. <-> col xb+k (k=0..1)
    float avz[4], bvz[4], q1[2], q2[2], q3[2];
    {
        const f32x2 d2 = ld2(dd + rz + xb);
        const f32x2 r2 = ld2(rho + rz + xb);
        const float dza[4] = {dd[rz + xm1], d2.x, d2.y, dd[rz + xp2]};
        const float rza[4] = {rho[rz + xm1], r2.x, r2.y, rho[rz + xp2]};
        float inv_c[4];
        #pragma unroll
        for (int j = 0; j < 4; ++j) {
            const float c   = 0.5f * DT * dza[j];
            const float inv = rcpf(1.0f + c);
            inv_c[j] = inv;
            avz[j] = (1.0f - c) * inv;
            bvz[j] = DT * INV_H * inv * rcpf(rza[j]);
        }
        const f32x2 vp2 = ld2(vp + rz + xb);
        const f32x2 vs2 = ld2(vs + rz + xb);
        const float vpa[2] = {vp2.x, vp2.y};
        const float vsa[2] = {vs2.x, vs2.y};
        #pragma unroll
        for (int k = 0; k < 2; ++k) {
            const float r   = rza[k + 1];
            const float muv = r * vsa[k] * vsa[k];
            const float lam = r * vpa[k] * vpa[k] - 2.0f * muv;
            const float bsH = DT * INV_H * inv_c[k + 1];
            q1[k] = bsH * (lam + 2.0f * muv);
            q2[k] = bsH * lam;
            q3[k] = bsH * muv;
        }
    }
    float azp[2], bzp[2], azm[2], bzm[2];
    {
        const f32x2 dp = ld2(dd + rzp + xb), dm = ld2(dd + rzm + xb);
        const f32x2 rp = ld2(rho + rzp + xb), rm = ld2(rho + rzm + xb);
        const float dpa[2] = {dp.x, dp.y}, dma[2] = {dm.x, dm.y};
        const float rpa[2] = {rp.x, rp.y}, rma[2] = {rm.x, rm.y};
        #pragma unroll
        for (int k = 0; k < 2; ++k) {
            float c = 0.5f * DT * dpa[k];
            float inv = rcpf(1.0f + c);
            azp[k] = (1.0f - c) * inv;
            bzp[k] = DT * INV_H * inv * rcpf(rpa[k]);
            c = 0.5f * DT * dma[k];
            inv = rcpf(1.0f + c);
            azm[k] = (1.0f - c) * inv;
            bzm[k] = DT * INV_H * inv * rcpf(rma[k]);
        }
    }

    // ---------- per-shot field update ----------
    #pragma unroll 1   // per-shot burst of 20 loads, one drain
    for (int b = 0; b < B; ++b) {
        const int b3  = b * PLANE;
        const int cz  = b3 + rz  + xb;
        const int czp = b3 + rzp + xb;
        const int czm = b3 + rzm + xb;

        // row segments (index j <-> col xb-1+j; k-indexed arrays <-> xb+k)
        float txxz[4], txzz[4], tzzz[3], tzzzp[3], txxzp[3];
        float txzzm[3], vxz[3], vzz[3];
        float txzzp[2], tzzzm[2], vxzp[2], vzzm[2];
        {
            f32x2 m;
            m = ld2(txx + cz);  txxz[1] = m.x; txxz[2] = m.y;
            txxz[0] = txx[b3 + rz + xm1];  txxz[3] = txx[b3 + rz + xp2];
            m = ld2(txz + cz);  txzz[1] = m.x; txzz[2] = m.y;
            txzz[0] = txz[b3 + rz + xm1];  txzz[3] = txz[b3 + rz + xp2];
            m = ld2(tzz + cz);  tzzz[1] = m.x; tzzz[2] = m.y;
            tzzz[0] = tzz[b3 + rz + xm1];
            m = ld2(tzz + czp); tzzzp[1] = m.x; tzzzp[2] = m.y;
            tzzzp[0] = tzz[b3 + rzp + xm1];
            m = ld2(txx + czp); txxzp[1] = m.x; txxzp[2] = m.y;
            txxzp[0] = txx[b3 + rzp + xm1];
            m = ld2(txz + czm); txzzm[0] = m.x; txzzm[1] = m.y;
            txzzm[2] = txz[b3 + rzm + xp2];
            m = ld2(vx + cz);   vxz[0] = m.x; vxz[1] = m.y;
            vxz[2] = vx[b3 + rz + xp2];
            m = ld2(vz + cz);   vzz[1] = m.x; vzz[2] = m.y;
            vzz[0] = vz[b3 + rz + xm1];
            m = ld2(txz + czp); txzzp[0] = m.x; txzzp[1] = m.y;
            m = ld2(tzz + czm); tzzzm[0] = m.x; tzzzm[1] = m.y;
            m = ld2(vx + czp);  vxzp[0] = m.x; vxzp[1] = m.y;
            m = ld2(vz + czm);  vzzm[0] = m.x; vzzm[1] = m.y;
        }

        // --- new velocities (leapfrog: from old stresses) ---
        float vxn_z[3];                 // vx_new(z, xb+k), k=0..2
        #pragma unroll
        for (int k = 0; k < 3; ++k)
            vxn_z[k] = avz[k + 1] * vxz[k]
                     + bvz[k + 1] * ((txxz[k + 1] - txxz[k])
                                   + (txzz[k + 1] - txzzm[k]));
        float vzn_z[3];                 // vz_new(z, xb-1+j), j=0..2
        #pragma unroll
        for (int j = 0; j < 3; ++j)
            vzn_z[j] = avz[j] * vzz[j]
                     + bvz[j] * ((txzz[j + 1] - txzz[j])
                               + (tzzzp[j] - tzzz[j]));
        float vxn_zp[2];                // vx_new(zp, xb+k)
        #pragma unroll
        for (int k = 0; k < 2; ++k)
            vxn_zp[k] = azp[k] * vxzp[k]
                      + bzp[k] * ((txxzp[k + 1] - txxzp[k])
                                + (txzzp[k] - txzz[k + 1]));
        float vzn_zm[2];                // vz_new(zm, xb+k)
        #pragma unroll
        for (int k = 0; k < 2; ++k)
            vzn_zm[k] = azm[k] * vzzm[k]
                      + bzm[k] * ((txzzm[k + 1] - txzzm[k])
                                + (tzzz[k + 1] - tzzzm[k]));

        // --- stress update (from new velocities) ---
        float oxx[2], ozz[2], oxz[2];
        #pragma unroll
        for (int k = 0; k < 2; ++k) {
            const float dvx = vxn_z[k + 1] - vxn_z[k];          // d+x vx_new
            const float dvz = vzn_z[k + 1] - vzn_zm[k];         // d-z vz_new
            oxx[k] = avz[k + 1] * txxz[k + 1] + q1[k] * dvx + q2[k] * dvz;
            ozz[k] = avz[k + 1] * tzzz[k + 1] + q1[k] * dvz + q2[k] * dvx;
            oxz[k] = avz[k + 1] * txzz[k + 1]
                   + q3[k] * ((vxn_zp[k] - vxn_z[k])
                            + (vzn_z[k + 1] - vzn_z[k]));
        }

        st2(out + 0 * VOL + cz, vxn_z[0], vxn_z[1]);
        st2(out + 1 * VOL + cz, vzn_z[1], vzn_z[2]);
        st2(out + 2 * VOL + cz, oxx[0], oxx[1]);
        st2(out + 3 * VOL + cz, ozz[0], ozz[1]);
        st2(out + 4 * VOL + cz, oxz[0], oxz[1]);
    }
}

extern "C" void kernel_launch(void* const* d_in, const int* in_sizes, int n_in,
                              void* d_out, int out_size, void* d_ws, size_t ws_size,
                              hipStream_t stream) {
    const float* vp  = (const float*)d_in[0];
    const float* vs  = (const float*)d_in[1];
    const float* rho = (const float*)d_in[2];
    const float* vx  = (const float*)d_in[3];
    const float* vz  = (const float*)d_in[4];
    const float* txx = (const float*)d_in[5];
    const float* tzz = (const float*)d_in[6];
    const float* txz = (const float*)d_in[7];
    const float* dd  = (const float*)d_in[8];
    float* out = (float*)d_out;

    const int threads = 256;
    const int blocks  = NBLK;  // 8192, exact
    hipLaunchKernelGGL(wave_fused_v11, dim3(blocks), dim3(threads), 0, stream,
                       vp, vs, rho, vx, vz, txx, tzz, txz, dd, out);
}

// Round 12
// 597.138 us; speedup vs baseline: 1.1037x; 1.1037x over previous
//
#include <hip/hip_runtime.h>

// WaveCell v12: 8z x 128x LDS-tiled, conflict-free, hoisted staging.
// B=4, NZ=NX=2048, fp32, periodic wrap (pow2 dims).
//
// Surviving model after 11 rounds: per-CU outstanding-line cap ~17-21
// GB/s/CU on the READ side (v11: 2x waves, no gain -> cap is per-CU not
// per-wave; v2==v4: hit level irrelevant; v1: instr count mild).
// v4 CU-side reads ~1.0GB / 213us = the wall. Lever: CU-side bytes.
// v10 (same idea) regressed from implementation overhead: 7M bank
// conflicts, per-shot div-heavy ragged staging, lost MLP.
//
// v12 fixes: (a) wave reads contiguous 512B LDS segments (ds_read_b128
// only; edges via aligned b128 .w/.x extract) -> 0 conflicts by
// construction; (b) staging src ptrs + LDS dsts hoisted (per shot: +b3,
// 7 f4 loads in flight, 7 contiguous ds_writes); (c) staged bytes/block-
// shot 27.2KB vs v4's ~49KB unique -> CU-side reads ~0.55GB.
// Keep: XCD swizzle, cached stores (v9), unroll-1 shot loop.

constexpr int NZ = 2048;
constexpr int NX = 2048;
constexpr int B  = 4;
constexpr int PLANE = NZ * NX;      // 4,194,304
constexpr int VOL   = B * PLANE;    // 16,777,216
constexpr float DT    = 1e-3f;
constexpr float INV_H = 0.1f;       // 1/10m

constexpr int ZB   = 8;             // z-rows per block
constexpr int XR   = 128;           // x-points per block
constexpr int NROW = ZB + 2;        // staged rows z0-1 .. z0+8
constexpr int RF4  = 34;            // float4 per staged row (x0-4 .. x0+131)
constexpr int ROWF = 140;           // LDS row stride (floats), 136 + 4 pad
constexpr int F4PF = NROW * RF4;    // 340 float4 per field
constexpr int TOT  = 5 * F4PF;      // 1700 float4 staged per shot
constexpr int NBLK = PLANE / (ZB * XR);    // 4096
constexpr int NXCD = 8;
constexpr int BLK_PER_XCD = NBLK / NXCD;   // 512

typedef float f32x4 __attribute__((ext_vector_type(4)));

__device__ __forceinline__ float rcpf(float x) { return __builtin_amdgcn_rcpf(x); }
__device__ __forceinline__ float4 ld4(const float* __restrict__ p) {
    return *reinterpret_cast<const float4*>(p);
}
__device__ __forceinline__ void st4(float* __restrict__ p,
                                    float a, float b, float c, float d) {
    f32x4 v = {a, b, c, d};
    *reinterpret_cast<f32x4*>(p) = v;   // plain cached store (v9-proven)
}

__global__ __launch_bounds__(256) void wave_fused_v12(
    const float* __restrict__ vp,  const float* __restrict__ vs,
    const float* __restrict__ rho,
    const float* __restrict__ vx,  const float* __restrict__ vz,
    const float* __restrict__ txx, const float* __restrict__ tzz,
    const float* __restrict__ txz,
    const float* __restrict__ dd,
    float* __restrict__ out)
{
    __shared__ float lds[5 * NROW * ROWF];   // 28,000 B

    // XCD-band swizzle: XCD k owns 512 consecutive sb = 32 z-tiles = 256
    // contiguous z-rows -> halo rows L2-local.
    const int bid = blockIdx.x;
    const int sb  = (bid & (NXCD - 1)) * BLK_PER_XCD + (bid >> 3);
    const int tz  = sb >> 4;                 // 256 z-tiles
    const int tx  = sb & 15;                 // 16 x-tiles
    const int z0  = tz << 3;
    const int x0  = tx << 7;
    const int tid = threadIdx.x;
    const int xt  = tid & 31;                // 32 x-threads (4 pts each)
    const int zt  = tid >> 5;                // 8 z-threads

    const int z   = z0 + zt;
    const int x   = x0 + (xt << 2);
    const int zp  = (z + 1) & (NZ - 1);
    const int zm  = (z - 1) & (NZ - 1);
    const int xm1 = (x - 1) & (NX - 1);
    const int xp4 = (x + 4) & (NX - 1);
    const int rz  = z  * NX;
    const int rzp = zp * NX;
    const int rzm = zm * NX;

    // ---------- hoisted staging addresses (b-invariant) ----------
    const float* sp[7];
    int dst7[7];
    {
        #pragma unroll
        for (int k = 0; k < 7; ++k) {
            const int idx = k * 256 + tid;
            const int f   = idx / F4PF;              // 0..4 (5 when inactive)
            const int rem = idx - f * F4PF;
            const int rr  = rem / RF4;
            const int c   = rem - rr * RF4;
            const int gz  = (z0 - 1 + rr) & (NZ - 1);
            const int gx  = (x0 - 4 + (c << 2)) & (NX - 1);
            const float* fp = (f == 0) ? txx : (f == 1) ? txz
                            : (f == 2) ? tzz : (f == 3) ? vx
                            : (f == 4) ? vz  : txx;   // f==5: inactive lanes
            sp[k]   = fp + gz * NX + gx;
            dst7[k] = (f * NROW + rr) * ROWF + (c << 2);
        }
    }
    const bool act6 = tid < (TOT - 6 * 256);         // tid < 164

    // ---------- per-thread coefficients (regs, amortized over shots) -------
    float dz6[6], rz6[6];
    {
        const float4 d4 = ld4(dd + rz + x);
        dz6[0] = dd[rz + xm1]; dz6[1] = d4.x; dz6[2] = d4.y;
        dz6[3] = d4.z;         dz6[4] = d4.w; dz6[5] = dd[rz + xp4];
        const float4 r4 = ld4(rho + rz + x);
        rz6[0] = rho[rz + xm1]; rz6[1] = r4.x; rz6[2] = r4.y;
        rz6[3] = r4.z;          rz6[4] = r4.w; rz6[5] = rho[rz + xp4];
    }
    float avz[6], bvz[6], inv_c[4];
    #pragma unroll
    for (int j = 0; j < 6; ++j) {
        const float c   = 0.5f * DT * dz6[j];
        const float inv = rcpf(1.0f + c);
        avz[j] = (1.0f - c) * inv;
        bvz[j] = DT * INV_H * inv * rcpf(rz6[j]);
        if (j >= 1 && j <= 4) inv_c[j - 1] = inv;
    }
    float avzp[4], bvzp[4], avzm[4], bvzm[4];
    {
        const float4 dp = ld4(dd + rzp + x), dm = ld4(dd + rzm + x);
        const float4 rp = ld4(rho + rzp + x), rm = ld4(rho + rzm + x);
        const float dpa[4] = {dp.x, dp.y, dp.z, dp.w};
        const float dma[4] = {dm.x, dm.y, dm.z, dm.w};
        const float rpa[4] = {rp.x, rp.y, rp.z, rp.w};
        const float rma[4] = {rm.x, rm.y, rm.z, rm.w};
        #pragma unroll
        for (int k = 0; k < 4; ++k) {
            float c = 0.5f * DT * dpa[k];
            float inv = rcpf(1.0f + c);
            avzp[k] = (1.0f - c) * inv;
            bvzp[k] = DT * INV_H * inv * rcpf(rpa[k]);
            c = 0.5f * DT * dma[k];
            inv = rcpf(1.0f + c);
            avzm[k] = (1.0f - c) * inv;
            bvzm[k] = DT * INV_H * inv * rcpf(rma[k]);
        }
    }
    float q1[4], q2[4], q3[4];
    {
        const float4 vp4 = ld4(vp + rz + x), vs4 = ld4(vs + rz + x);
        const float vpa[4] = {vp4.x, vp4.y, vp4.z, vp4.w};
        const float vsa[4] = {vs4.x, vs4.y, vs4.z, vs4.w};
        #pragma unroll
        for (int k = 0; k < 4; ++k) {
            const float r   = rz6[k + 1];
            const float muv = r * vsa[k] * vsa[k];
            const float lam = r * vpa[k] * vpa[k] - 2.0f * muv;
            const float bsH = DT * INV_H * inv_c[k];
            q1[k] = bsH * (lam + 2.0f * muv);
            q2[k] = bsH * lam;
            q3[k] = bsH * muv;
        }
    }

    // LDS compute bases: staged row 0 of each field = global z0-1.
    const int lx   = 4 + (xt << 2);
    const int rowT = (0 * NROW + zt) * ROWF + lx;   // +ROWF = row z
    const int rowX = (1 * NROW + zt) * ROWF + lx;
    const int rowZ = (2 * NROW + zt) * ROWF + lx;
    const int rowV = (3 * NROW + zt) * ROWF + lx;
    const int rowW = (4 * NROW + zt) * ROWF + lx;
    auto L4 = [&](int off) -> f32x4 {
        return *reinterpret_cast<const f32x4*>(&lds[off]);
    };

    // ---------- per-shot: stage -> barrier -> compute ----------
    #pragma unroll 1
    for (int b = 0; b < B; ++b) {
        const int b3 = b * PLANE;

        if (b) __syncthreads();          // prev compute done before overwrite

        f32x4 sv[7];
        #pragma unroll
        for (int k = 0; k < 7; ++k)      // 7 dwordx4 in flight
            sv[k] = *reinterpret_cast<const f32x4*>(sp[k] + b3);
        #pragma unroll
        for (int k = 0; k < 6; ++k)
            *reinterpret_cast<f32x4*>(&lds[dst7[k]]) = sv[k];
        if (act6)
            *reinterpret_cast<f32x4*>(&lds[dst7[6]]) = sv[6];
        __syncthreads();

        // ---- gather row segments from LDS (all aligned ds_read_b128) ----
        float txxz[6], txzz[6], tzzz[5], tzzzp[5], txxzp[5];
        float txzzm[5], vxz[5], vzz[5];
        float txzzp4[4], tzzzm4[4], vxzp4[4], vzzm4[4];
        {
            f32x4 m, e;
            m = L4(rowT + ROWF);      e = L4(rowT + ROWF - 4);
            txxz[1] = m.x; txxz[2] = m.y; txxz[3] = m.z; txxz[4] = m.w;
            txxz[0] = e.w;            e = L4(rowT + ROWF + 4);
            txxz[5] = e.x;
            m = L4(rowX + ROWF);      e = L4(rowX + ROWF - 4);
            txzz[1] = m.x; txzz[2] = m.y; txzz[3] = m.z; txzz[4] = m.w;
            txzz[0] = e.w;            e = L4(rowX + ROWF + 4);
            txzz[5] = e.x;
            m = L4(rowZ + ROWF);      e = L4(rowZ + ROWF - 4);
            tzzz[1] = m.x; tzzz[2] = m.y; tzzz[3] = m.z; tzzz[4] = m.w;
            tzzz[0] = e.w;
            m = L4(rowZ + 2 * ROWF);  e = L4(rowZ + 2 * ROWF - 4);
            tzzzp[1] = m.x; tzzzp[2] = m.y; tzzzp[3] = m.z; tzzzp[4] = m.w;
            tzzzp[0] = e.w;
            m = L4(rowT + 2 * ROWF);  e = L4(rowT + 2 * ROWF - 4);
            txxzp[1] = m.x; txxzp[2] = m.y; txxzp[3] = m.z; txxzp[4] = m.w;
            txxzp[0] = e.w;
            m = L4(rowX);             e = L4(rowX + 4);
            txzzm[0] = m.x; txzzm[1] = m.y; txzzm[2] = m.z; txzzm[3] = m.w;
            txzzm[4] = e.x;
            m = L4(rowV + ROWF);      e = L4(rowV + ROWF + 4);
            vxz[0] = m.x; vxz[1] = m.y; vxz[2] = m.z; vxz[3] = m.w;
            vxz[4] = e.x;
            m = L4(rowW + ROWF);      e = L4(rowW + ROWF - 4);
            vzz[1] = m.x; vzz[2] = m.y; vzz[3] = m.z; vzz[4] = m.w;
            vzz[0] = e.w;
            m = L4(rowX + 2 * ROWF);
            txzzp4[0] = m.x; txzzp4[1] = m.y; txzzp4[2] = m.z; txzzp4[3] = m.w;
            m = L4(rowZ);
            tzzzm4[0] = m.x; tzzzm4[1] = m.y; tzzzm4[2] = m.z; tzzzm4[3] = m.w;
            m = L4(rowV + 2 * ROWF);
            vxzp4[0] = m.x; vxzp4[1] = m.y; vxzp4[2] = m.z; vxzp4[3] = m.w;
            m = L4(rowW);
            vzzm4[0] = m.x; vzzm4[1] = m.y; vzzm4[2] = m.z; vzzm4[3] = m.w;
        }

        // --- new velocities (leapfrog: from old stresses) ---
        float vxn_z[5];
        #pragma unroll
        for (int k = 0; k < 5; ++k)
            vxn_z[k] = avz[k + 1] * vxz[k]
                     + bvz[k + 1] * ((txxz[k + 1] - txxz[k])
                                   + (txzz[k + 1] - txzzm[k]));
        float vzn_z[5];
        #pragma unroll
        for (int k = 0; k < 5; ++k)
            vzn_z[k] = avz[k] * vzz[k]
                     + bvz[k] * ((txzz[k + 1] - txzz[k])
                               + (tzzzp[k] - tzzz[k]));
        float vxn_zp[4];
        #pragma unroll
        for (int k = 0; k < 4; ++k)
            vxn_zp[k] = avzp[k] * vxzp4[k]
                      + bvzp[k] * ((txxzp[k + 1] - txxzp[k])
                                 + (txzzp4[k] - txzz[k + 1]));
        float vzn_zm[4];
        #pragma unroll
        for (int k = 0; k < 4; ++k)
            vzn_zm[k] = avzm[k] * vzzm4[k]
                      + bvzm[k] * ((txzzm[k + 1] - txzzm[k])
                                 + (tzzz[k + 1] - tzzzm4[k]));

        // --- stress update (from new velocities) ---
        float oxx[4], ozz[4], oxz[4];
        #pragma unroll
        for (int k = 0; k < 4; ++k) {
            const float dvx = vxn_z[k + 1] - vxn_z[k];
            const float dvz = vzn_z[k + 1] - vzn_zm[k];
            oxx[k] = avz[k + 1] * txxz[k + 1] + q1[k] * dvx + q2[k] * dvz;
            ozz[k] = avz[k + 1] * tzzz[k + 1] + q1[k] * dvz + q2[k] * dvx;
            oxz[k] = avz[k + 1] * txzz[k + 1]
                   + q3[k] * ((vxn_zp[k] - vxn_z[k])
                            + (vzn_z[k + 1] - vzn_z[k]));
        }

        const int cz = b3 + rz + x;
        st4(out + 0 * VOL + cz, vxn_z[0], vxn_z[1], vxn_z[2], vxn_z[3]);
        st4(out + 1 * VOL + cz, vzn_z[1], vzn_z[2], vzn_z[3], vzn_z[4]);
        st4(out + 2 * VOL + cz, oxx[0], oxx[1], oxx[2], oxx[3]);
        st4(out + 3 * VOL + cz, ozz[0], ozz[1], ozz[2], ozz[3]);
        st4(out + 4 * VOL + cz, oxz[0], oxz[1], oxz[2], oxz[3]);
    }
}

extern "C" void kernel_launch(void* const* d_in, const int* in_sizes, int n_in,
                              void* d_out, int out_size, void* d_ws, size_t ws_size,
                              hipStream_t stream) {
    const float* vp  = (const float*)d_in[0];
    const float* vs  = (const float*)d_in[1];
    const float* rho = (const float*)d_in[2];
    const float* vx  = (const float*)d_in[3];
    const float* vz  = (const float*)d_in[4];
    const float* txx = (const float*)d_in[5];
    const float* tzz = (const float*)d_in[6];
    const float* txz = (const float*)d_in[7];
    const float* dd  = (const float*)d_in[8];
    float* out = (float*)d_out;

    const int threads = 256;
    const int blocks  = NBLK;  // 4096, exact
    hipLaunchKernelGGL(wave_fused_v12, dim3(blocks), dim3(threads), 0, stream,
                       vp, vs, rho, vx, vz, txx, tzz, txz, dd, out);
}

// Round 13
// 591.039 us; speedup vs baseline: 1.1151x; 1.0103x over previous
//
#include <hip/hip_runtime.h>

// WaveCell v13: v12 (8z x 128x LDS tile, conflict-free, hoisted staging)
// + cross-shot software-pipelined staging.
// B=4, NZ=NX=2048, fp32, periodic wrap (pow2 dims).
//
// v12 (harness 597us, dispatch ~188us est): LDS tiling done right finally
// beat the 213us wall -> CU-side-byte model confirmed. Residual vs ~145us
// composite floor: per-shot stage phase exposes ~700cy global latency with
// only cross-block overlap (~4-5 blocks/CU) to cover it.
// v13: prefetch shot b+1's 7 dwordx4 into the SAME sv regs right after the
// LDS write of shot b (sv dead after ds_write -> zero extra regs). The
// vmcnt wait lands at next iteration's ds_write, a full compute phase later.
// Pre-commit: WRITE==320MiB (no spill); flat result (+-5us) -> declare
// plateau (barrier-structure bound).

constexpr int NZ = 2048;
constexpr int NX = 2048;
constexpr int B  = 4;
constexpr int PLANE = NZ * NX;      // 4,194,304
constexpr int VOL   = B * PLANE;    // 16,777,216
constexpr float DT    = 1e-3f;
constexpr float INV_H = 0.1f;       // 1/10m

constexpr int ZB   = 8;             // z-rows per block
constexpr int XR   = 128;           // x-points per block
constexpr int NROW = ZB + 2;        // staged rows z0-1 .. z0+8
constexpr int RF4  = 34;            // float4 per staged row (x0-4 .. x0+131)
constexpr int ROWF = 140;           // LDS row stride (floats), 136 + 4 pad
constexpr int F4PF = NROW * RF4;    // 340 float4 per field
constexpr int TOT  = 5 * F4PF;      // 1700 float4 staged per shot
constexpr int NBLK = PLANE / (ZB * XR);    // 4096
constexpr int NXCD = 8;
constexpr int BLK_PER_XCD = NBLK / NXCD;   // 512

typedef float f32x4 __attribute__((ext_vector_type(4)));

__device__ __forceinline__ float rcpf(float x) { return __builtin_amdgcn_rcpf(x); }
__device__ __forceinline__ float4 ld4(const float* __restrict__ p) {
    return *reinterpret_cast<const float4*>(p);
}
__device__ __forceinline__ void st4(float* __restrict__ p,
                                    float a, float b, float c, float d) {
    f32x4 v = {a, b, c, d};
    *reinterpret_cast<f32x4*>(p) = v;   // plain cached store (v9-proven)
}

__global__ __launch_bounds__(256) void wave_fused_v13(
    const float* __restrict__ vp,  const float* __restrict__ vs,
    const float* __restrict__ rho,
    const float* __restrict__ vx,  const float* __restrict__ vz,
    const float* __restrict__ txx, const float* __restrict__ tzz,
    const float* __restrict__ txz,
    const float* __restrict__ dd,
    float* __restrict__ out)
{
    __shared__ float lds[5 * NROW * ROWF];   // 28,000 B

    // XCD-band swizzle: XCD k owns 512 consecutive sb = 32 z-tiles = 256
    // contiguous z-rows -> halo rows L2-local.
    const int bid = blockIdx.x;
    const int sb  = (bid & (NXCD - 1)) * BLK_PER_XCD + (bid >> 3);
    const int tz  = sb >> 4;                 // 256 z-tiles
    const int tx  = sb & 15;                 // 16 x-tiles
    const int z0  = tz << 3;
    const int x0  = tx << 7;
    const int tid = threadIdx.x;
    const int xt  = tid & 31;                // 32 x-threads (4 pts each)
    const int zt  = tid >> 5;                // 8 z-threads

    const int z   = z0 + zt;
    const int x   = x0 + (xt << 2);
    const int zp  = (z + 1) & (NZ - 1);
    const int zm  = (z - 1) & (NZ - 1);
    const int xm1 = (x - 1) & (NX - 1);
    const int xp4 = (x + 4) & (NX - 1);
    const int rz  = z  * NX;
    const int rzp = zp * NX;
    const int rzm = zm * NX;

    // ---------- hoisted staging addresses (b-invariant) ----------
    const float* sp[7];
    int dst7[7];
    {
        #pragma unroll
        for (int k = 0; k < 7; ++k) {
            const int idx = k * 256 + tid;
            const int f   = idx / F4PF;              // 0..4 (5 when inactive)
            const int rem = idx - f * F4PF;
            const int rr  = rem / RF4;
            const int c   = rem - rr * RF4;
            const int gz  = (z0 - 1 + rr) & (NZ - 1);
            const int gx  = (x0 - 4 + (c << 2)) & (NX - 1);
            const float* fp = (f == 0) ? txx : (f == 1) ? txz
                            : (f == 2) ? tzz : (f == 3) ? vx
                            : (f == 4) ? vz  : txx;   // f==5: inactive lanes
            sp[k]   = fp + gz * NX + gx;
            dst7[k] = (f * NROW + rr) * ROWF + (c << 2);
        }
    }
    const bool act6 = tid < (TOT - 6 * 256);         // tid < 164

    // ---------- per-thread coefficients (regs, amortized over shots) -------
    float dz6[6], rz6[6];
    {
        const float4 d4 = ld4(dd + rz + x);
        dz6[0] = dd[rz + xm1]; dz6[1] = d4.x; dz6[2] = d4.y;
        dz6[3] = d4.z;         dz6[4] = d4.w; dz6[5] = dd[rz + xp4];
        const float4 r4 = ld4(rho + rz + x);
        rz6[0] = rho[rz + xm1]; rz6[1] = r4.x; rz6[2] = r4.y;
        rz6[3] = r4.z;          rz6[4] = r4.w; rz6[5] = rho[rz + xp4];
    }
    float avz[6], bvz[6], inv_c[4];
    #pragma unroll
    for (int j = 0; j < 6; ++j) {
        const float c   = 0.5f * DT * dz6[j];
        const float inv = rcpf(1.0f + c);
        avz[j] = (1.0f - c) * inv;
        bvz[j] = DT * INV_H * inv * rcpf(rz6[j]);
        if (j >= 1 && j <= 4) inv_c[j - 1] = inv;
    }
    float avzp[4], bvzp[4], avzm[4], bvzm[4];
    {
        const float4 dp = ld4(dd + rzp + x), dm = ld4(dd + rzm + x);
        const float4 rp = ld4(rho + rzp + x), rm = ld4(rho + rzm + x);
        const float dpa[4] = {dp.x, dp.y, dp.z, dp.w};
        const float dma[4] = {dm.x, dm.y, dm.z, dm.w};
        const float rpa[4] = {rp.x, rp.y, rp.z, rp.w};
        const float rma[4] = {rm.x, rm.y, rm.z, rm.w};
        #pragma unroll
        for (int k = 0; k < 4; ++k) {
            float c = 0.5f * DT * dpa[k];
            float inv = rcpf(1.0f + c);
            avzp[k] = (1.0f - c) * inv;
            bvzp[k] = DT * INV_H * inv * rcpf(rpa[k]);
            c = 0.5f * DT * dma[k];
            inv = rcpf(1.0f + c);
            avzm[k] = (1.0f - c) * inv;
            bvzm[k] = DT * INV_H * inv * rcpf(rma[k]);
        }
    }
    float q1[4], q2[4], q3[4];
    {
        const float4 vp4 = ld4(vp + rz + x), vs4 = ld4(vs + rz + x);
        const float vpa[4] = {vp4.x, vp4.y, vp4.z, vp4.w};
        const float vsa[4] = {vs4.x, vs4.y, vs4.z, vs4.w};
        #pragma unroll
        for (int k = 0; k < 4; ++k) {
            const float r   = rz6[k + 1];
            const float muv = r * vsa[k] * vsa[k];
            const float lam = r * vpa[k] * vpa[k] - 2.0f * muv;
            const float bsH = DT * INV_H * inv_c[k];
            q1[k] = bsH * (lam + 2.0f * muv);
            q2[k] = bsH * lam;
            q3[k] = bsH * muv;
        }
    }

    // LDS compute bases: staged row 0 of each field = global z0-1.
    const int lx   = 4 + (xt << 2);
    const int rowT = (0 * NROW + zt) * ROWF + lx;   // +ROWF = row z
    const int rowX = (1 * NROW + zt) * ROWF + lx;
    const int rowZ = (2 * NROW + zt) * ROWF + lx;
    const int rowV = (3 * NROW + zt) * ROWF + lx;
    const int rowW = (4 * NROW + zt) * ROWF + lx;
    auto L4 = [&](int off) -> f32x4 {
        return *reinterpret_cast<const f32x4*>(&lds[off]);
    };

    // ---------- pipelined: prefetch(b+1) hides under compute(b) ----------
    f32x4 sv[7];
    #pragma unroll
    for (int k = 0; k < 7; ++k)              // prologue: shot 0 loads
        sv[k] = *reinterpret_cast<const f32x4*>(sp[k]);

    #pragma unroll 1
    for (int b = 0; b < B; ++b) {
        if (b) __syncthreads();          // prev compute done before overwrite

        #pragma unroll
        for (int k = 0; k < 6; ++k)
            *reinterpret_cast<f32x4*>(&lds[dst7[k]]) = sv[k];
        if (act6)
            *reinterpret_cast<f32x4*>(&lds[dst7[6]]) = sv[6];
        __syncthreads();

        if (b < B - 1) {                 // prefetch next shot into dead regs
            const int nb3 = (b + 1) * PLANE;
            #pragma unroll
            for (int k = 0; k < 7; ++k)
                sv[k] = *reinterpret_cast<const f32x4*>(sp[k] + nb3);
        }

        // ---- gather row segments from LDS (all aligned ds_read_b128) ----
        float txxz[6], txzz[6], tzzz[5], tzzzp[5], txxzp[5];
        float txzzm[5], vxz[5], vzz[5];
        float txzzp4[4], tzzzm4[4], vxzp4[4], vzzm4[4];
        {
            f32x4 m, e;
            m = L4(rowT + ROWF);      e = L4(rowT + ROWF - 4);
            txxz[1] = m.x; txxz[2] = m.y; txxz[3] = m.z; txxz[4] = m.w;
            txxz[0] = e.w;            e = L4(rowT + ROWF + 4);
            txxz[5] = e.x;
            m = L4(rowX + ROWF);      e = L4(rowX + ROWF - 4);
            txzz[1] = m.x; txzz[2] = m.y; txzz[3] = m.z; txzz[4] = m.w;
            txzz[0] = e.w;            e = L4(rowX + ROWF + 4);
            txzz[5] = e.x;
            m = L4(rowZ + ROWF);      e = L4(rowZ + ROWF - 4);
            tzzz[1] = m.x; tzzz[2] = m.y; tzzz[3] = m.z; tzzz[4] = m.w;
            tzzz[0] = e.w;
            m = L4(rowZ + 2 * ROWF);  e = L4(rowZ + 2 * ROWF - 4);
            tzzzp[1] = m.x; tzzzp[2] = m.y; tzzzp[3] = m.z; tzzzp[4] = m.w;
            tzzzp[0] = e.w;
            m = L4(rowT + 2 * ROWF);  e = L4(rowT + 2 * ROWF - 4);
            txxzp[1] = m.x; txxzp[2] = m.y; txxzp[3] = m.z; txxzp[4] = m.w;
            txxzp[0] = e.w;
            m = L4(rowX);             e = L4(rowX + 4);
            txzzm[0] = m.x; txzzm[1] = m.y; txzzm[2] = m.z; txzzm[3] = m.w;
            txzzm[4] = e.x;
            m = L4(rowV + ROWF);      e = L4(rowV + ROWF + 4);
            vxz[0] = m.x; vxz[1] = m.y; vxz[2] = m.z; vxz[3] = m.w;
            vxz[4] = e.x;
            m = L4(rowW + ROWF);      e = L4(rowW + ROWF - 4);
            vzz[1] = m.x; vzz[2] = m.y; vzz[3] = m.z; vzz[4] = m.w;
            vzz[0] = e.w;
            m = L4(rowX + 2 * ROWF);
            txzzp4[0] = m.x; txzzp4[1] = m.y; txzzp4[2] = m.z; txzzp4[3] = m.w;
            m = L4(rowZ);
            tzzzm4[0] = m.x; tzzzm4[1] = m.y; tzzzm4[2] = m.z; tzzzm4[3] = m.w;
            m = L4(rowV + 2 * ROWF);
            vxzp4[0] = m.x; vxzp4[1] = m.y; vxzp4[2] = m.z; vxzp4[3] = m.w;
            m = L4(rowW);
            vzzm4[0] = m.x; vzzm4[1] = m.y; vzzm4[2] = m.z; vzzm4[3] = m.w;
        }

        // --- new velocities (leapfrog: from old stresses) ---
        float vxn_z[5];
        #pragma unroll
        for (int k = 0; k < 5; ++k)
            vxn_z[k] = avz[k + 1] * vxz[k]
                     + bvz[k + 1] * ((txxz[k + 1] - txxz[k])
                                   + (txzz[k + 1] - txzzm[k]));
        float vzn_z[5];
        #pragma unroll
        for (int k = 0; k < 5; ++k)
            vzn_z[k] = avz[k] * vzz[k]
                     + bvz[k] * ((txzz[k + 1] - txzz[k])
                               + (tzzzp[k] - tzzz[k]));
        float vxn_zp[4];
        #pragma unroll
        for (int k = 0; k < 4; ++k)
            vxn_zp[k] = avzp[k] * vxzp4[k]
                      + bvzp[k] * ((txxzp[k + 1] - txxzp[k])
                                 + (txzzp4[k] - txzz[k + 1]));
        float vzn_zm[4];
        #pragma unroll
        for (int k = 0; k < 4; ++k)
            vzn_zm[k] = avzm[k] * vzzm4[k]
                      + bvzm[k] * ((txzzm[k + 1] - txzzm[k])
                                 + (tzzz[k + 1] - tzzzm4[k]));

        // --- stress update (from new velocities) ---
        float oxx[4], ozz[4], oxz[4];
        #pragma unroll
        for (int k = 0; k < 4; ++k) {
            const float dvx = vxn_z[k + 1] - vxn_z[k];
            const float dvz = vzn_z[k + 1] - vzn_zm[k];
            oxx[k] = avz[k + 1] * txxz[k + 1] + q1[k] * dvx + q2[k] * dvz;
            ozz[k] = avz[k + 1] * tzzz[k + 1] + q1[k] * dvz + q2[k] * dvx;
            oxz[k] = avz[k + 1] * txzz[k + 1]
                   + q3[k] * ((vxn_zp[k] - vxn_z[k])
                            + (vzn_z[k + 1] - vzn_z[k]));
        }

        const int cz = b * PLANE + rz + x;
        st4(out + 0 * VOL + cz, vxn_z[0], vxn_z[1], vxn_z[2], vxn_z[3]);
        st4(out + 1 * VOL + cz, vzn_z[1], vzn_z[2], vzn_z[3], vzn_z[4]);
        st4(out + 2 * VOL + cz, oxx[0], oxx[1], oxx[2], oxx[3]);
        st4(out + 3 * VOL + cz, ozz[0], ozz[1], ozz[2], ozz[3]);
        st4(out + 4 * VOL + cz, oxz[0], oxz[1], oxz[2], oxz[3]);
    }
}

extern "C" void kernel_launch(void* const* d_in, const int* in_sizes, int n_in,
                              void* d_out, int out_size, void* d_ws, size_t ws_size,
                              hipStream_t stream) {
    const float* vp  = (const float*)d_in[0];
    const float* vs  = (const float*)d_in[1];
    const float* rho = (const float*)d_in[2];
    const float* vx  = (const float*)d_in[3];
    const float* vz  = (const float*)d_in[4];
    const float* txx = (const float*)d_in[5];
    const float* tzz = (const float*)d_in[6];
    const float* txz = (const float*)d_in[7];
    const float* dd  = (const float*)d_in[8];
    float* out = (float*)d_out;

    const int threads = 256;
    const int blocks  = NBLK;  // 4096, exact
    hipLaunchKernelGGL(wave_fused_v13, dim3(blocks), dim3(threads), 0, stream,
                       vp, vs, rho, vx, vz, txx, tzz, txz, dd, out);
}